// Round 6
// baseline (406.592 us; speedup 1.0000x reference)
//
#include <hip/hip_runtime.h>
#include <cstdint>
#include <cstddef>

using short8 = __attribute__((ext_vector_type(8))) short;
using f32x4  = __attribute__((ext_vector_type(4))) float;

#define AS_G __attribute__((address_space(1)))
#define AS_L __attribute__((address_space(3)))

static __device__ __forceinline__ void ld_lds16(const void* g, void* l) {
  __builtin_amdgcn_global_load_lds((const AS_G void*)g, (AS_L void*)l, 16, 0, 0);
}

static __device__ __forceinline__ unsigned short f2bf(float f) {
  unsigned int u = __float_as_uint(f);
  u = u + 0x7fffu + ((u >> 16) & 1u);   // RNE
  return (unsigned short)(u >> 16);
}

// ---------------------------------------------------------------------------
// prep: f32 -> bf16 converts. W_A rows are PERMUTED by sigma(n') = (n'&63)*64
// + (n'>>6) so the GEMM emits A-transpose (A'[t][c*64+r] = A_t[r][c]) with
// packed stores. Also emits the sigma-permuted f32 bias copy.
// ---------------------------------------------------------------------------
__global__ __launch_bounds__(256) void prep_kernel(
    const float* __restrict__ u, const float* __restrict__ WA,
    const float* __restrict__ WB, const float* __restrict__ Wd,
    const float* __restrict__ WAbias,
    unsigned short* __restrict__ ub, unsigned short* __restrict__ WAb,
    unsigned short* __restrict__ Wbd, float* __restrict__ biasP)
{
  const int gtid = blockIdx.x * blockDim.x + threadIdx.x;
  if (gtid < 4096) biasP[gtid] = WAbias[(gtid & 63) * 64 + (gtid >> 6)];

  const int NU = 8388608 / 4;
  const int NA = 2097152 / 4;
  const int NB = 32768 / 4;
  const int ND = 32768 / 4;
  const int total = NU + NA + NB + ND;
  for (int i = gtid; i < total; i += gridDim.x * blockDim.x) {
    const float4* s4; ushort4* d4; int j, sj;
    if (i < NU)                { s4 = (const float4*)u;  d4 = (ushort4*)ub;  j = i; sj = j; }
    else if (i < NU + NA)      { s4 = (const float4*)WA; d4 = (ushort4*)WAb; j = i - NU;
                                 const int row = j >> 7, c4 = j & 127;
                                 sj = ((row & 63) * 64 + (row >> 6)) * 128 + c4; }
    else if (i < NU + NA + NB) { s4 = (const float4*)WB; d4 = (ushort4*)Wbd; j = i - NU - NA; sj = j; }
    else                       { s4 = (const float4*)Wd; d4 = (ushort4*)Wbd + NB; j = i - NU - NA - NB; sj = j; }
    float4 v = s4[sj];
    ushort4 o;
    o.x = f2bf(v.x); o.y = f2bf(v.y); o.z = f2bf(v.z); o.w = f2bf(v.w);
    d4[j] = o;
  }
}

// ---------------------------------------------------------------------------
// GEMM: C[m,n] = sum_k U[m,k]*W[n,k], bf16 MFMA 16x16x32, 128x128 tile, BK=64.
// 2-phase double-buffered LDS (stage k+1 before compute k, 1 barrier/K-step).
// LDS XOR chunk swizzle; swapped mfma operands -> lane holds 4 consecutive n.
// Default dispatch order (no XCD swizzle: R1 FETCH 85MB vs R3 swizzled 266MB).
// EPI=1: A' = tanh(x+biasP)*0.125, diag zeroed, bf16, plain packed stores.
// EPI=2: n<64 -> Bu = x+bB (f32); n>=64 -> d = sigmoid(x+bd) (f32)
// ---------------------------------------------------------------------------
template <int EPI>
__global__ __launch_bounds__(256) void gemm_kernel(
    const unsigned short* __restrict__ U,   // [M][512] bf16
    const unsigned short* __restrict__ W,   // [N][512] bf16
    const float* __restrict__ bias0,
    const float* __restrict__ bias1,
    unsigned short* __restrict__ outA,
    float* __restrict__ outBu,
    float* __restrict__ outd)
{
  __shared__ unsigned short lA[2][128 * 64];  // 2 x 16 KB
  __shared__ unsigned short lB[2][128 * 64];  // 2 x 16 KB

  const int tid  = threadIdx.x;
  const int lane = tid & 63;
  const int wv   = tid >> 6;
  const int wuni = __builtin_amdgcn_readfirstlane(wv);
  const int bm = blockIdx.x * 128;
  const int bn = blockIdx.y * 128;

  f32x4 acc[4][4] = {};

  const int r16 = lane & 15, kq = lane >> 4;
  const int wm = (wv >> 1) * 64, wn = (wv & 1) * 64;

  auto stage = [&](int buf, int k0) {
#pragma unroll
    for (int l = 0; l < 4; ++l) {
      const int flat = l * 256 + tid;
      const int row  = flat >> 3;
      const int cs   = (flat & 7) ^ (row & 7);
      const int ldsb = (l * 256 + wuni * 64) * 8;
      ld_lds16(U + (size_t)(bm + row) * 512 + k0 + cs * 8, &lA[buf][ldsb]);
      ld_lds16(W + (size_t)(bn + row) * 512 + k0 + cs * 8, &lB[buf][ldsb]);
    }
  };

  stage(0, 0);
  __syncthreads();                           // drains vmcnt(0): buf0 ready

  for (int ks = 0; ks < 8; ++ks) {
    if (ks < 7) stage((ks + 1) & 1, (ks + 1) * 64);   // async prefetch
    const int cb = ks & 1;
#pragma unroll
    for (int kk = 0; kk < 2; ++kk) {
      short8 af[4], bfr[4];
#pragma unroll
      for (int f = 0; f < 4; ++f) {
        const int swz = ((kk * 4 + kq) ^ (r16 & 7)) * 8;
        af[f]  = *(const short8*)&lA[cb][(wm + f * 16 + r16) * 64 + swz];
        bfr[f] = *(const short8*)&lB[cb][(wn + f * 16 + r16) * 64 + swz];
      }
#pragma unroll
      for (int i = 0; i < 4; ++i)
#pragma unroll
        for (int j = 0; j < 4; ++j)
          acc[i][j] = __builtin_amdgcn_mfma_f32_16x16x32_bf16(bfr[j], af[i], acc[i][j], 0, 0, 0);
    }
    __syncthreads();                         // drains vmcnt(0): next buf ready
  }

  const int mrow = lane & 15;
  const int ng   = (lane >> 4) * 4;
#pragma unroll
  for (int i = 0; i < 4; ++i) {
    const int m = bm + wm + i * 16 + mrow;
#pragma unroll
    for (int j = 0; j < 4; ++j) {
      const int nb = bn + wn + j * 16 + ng;
      if (EPI == 1) {
        float4 bi = *(const float4*)(bias0 + nb);
        const float* bp = (const float*)&bi;
        unsigned long long o = 0;
#pragma unroll
        for (int q = 0; q < 4; ++q) {
          const int n = nb + q;
          float z = acc[i][j][q] + bp[q];
          float e = __expf(2.f * z);
          float t = 1.f - 2.f / (e + 1.f);
          float v = (((n & 63) == (n >> 6))) ? 0.f : 0.125f * t;
          o |= ((unsigned long long)f2bf(v)) << (q * 16);
        }
        *(unsigned long long*)(outA + (size_t)m * 4096 + nb) = o;
      } else {
        const int n = wn + j * 16 + ng;
        if (n < 64) {
          float4 bi = *(const float4*)(bias0 + n);
          const float* bp = (const float*)&bi;
          float4 r; float* rp = (float*)&r;
#pragma unroll
          for (int q = 0; q < 4; ++q) rp[q] = acc[i][j][q] + bp[q];
          *(float4*)(outBu + (size_t)m * 64 + n) = r;
        } else {
          float4 bi = *(const float4*)(bias1 + (n - 64));
          const float* bp = (const float*)&bi;
          float4 r; float* rp = (float*)&r;
#pragma unroll
          for (int q = 0; q < 4; ++q) {
            float z = acc[i][j][q] + bp[q];
            rp[q] = 1.f / (1.f + __expf(-z));
          }
          *(float4*)(outd + (size_t)m * 64 + (n - 64)) = r;
        }
      }
    }
  }
}

// ---------------------------------------------------------------------------
// scan v4: h_t[r] = sum_c A_t[r][c] h[c] + d[r]h[r] + Bu[r].
// A' layout [t][c*64+r]. 8 waves/block (2/SIMD): wave w owns c in [8w,8w+8).
// Lane r. Register-staged depth-4 pipeline (8 A-loads + bu + d per tile per
// wave); h replicated in registers (bitwise-identical update per wave);
// cross-wave reduce via double-buffered LDS partials, 1 barrier/iter.
// Burn-in 64 (measured: absmax 9.2e-4).
// ---------------------------------------------------------------------------
__global__ __launch_bounds__(512) void scan_kernel(
    const unsigned short* __restrict__ At,  // [B*T][4096] = A_t[r][c] at c*64+r
    const float* __restrict__ Bu,           // [B*T][64]
    const float* __restrict__ dg,           // [B*T][64]
    float* __restrict__ hout)               // [B*T][64]
{
  __shared__ float part[2][8][64];

  const int tid = threadIdx.x;
  const int r = tid & 63;
  const int w = tid >> 6;
  const int b = blockIdx.y, ci = blockIdx.x;
  const int t0 = ci * 64, tend = t0 + 64;
  const int tstart = (t0 >= 64) ? (t0 - 64) : 0;
  const size_t base = (size_t)b * 2048;

  float h = 0.f;

  unsigned short a0[8], a1[8], a2[8], a3[8];
  float bu0, bu1, bu2, bu3, dd0, dd1, dd2, dd3;

#define ISSUE(AV, BUV, DDV, T) do {                                          \
    const size_t _m = base + (size_t)(T);                                    \
    const unsigned short* _p = At + _m * 4096 + (w * 8) * 64 + r;            \
    _Pragma("unroll") for (int q = 0; q < 8; ++q) AV[q] = _p[q * 64];        \
    BUV = Bu[_m * 64 + r];                                                   \
    DDV = dg[_m * 64 + r];                                                   \
  } while (0)

#define COMPUTE(AV, BUV, DDV, PB, T) do {                                    \
    float _p0 = 0.f, _p1 = 0.f;                                              \
    _Pragma("unroll") for (int q = 0; q < 4; ++q) {                          \
      float _hv = __uint_as_float(                                           \
          __builtin_amdgcn_readlane(__float_as_uint(h), w * 8 + q));         \
      _p0 = fmaf(__uint_as_float(((unsigned)AV[q]) << 16), _hv, _p0);        \
    }                                                                        \
    _Pragma("unroll") for (int q = 4; q < 8; ++q) {                          \
      float _hv = __uint_as_float(                                           \
          __builtin_amdgcn_readlane(__float_as_uint(h), w * 8 + q));         \
      _p1 = fmaf(__uint_as_float(((unsigned)AV[q]) << 16), _hv, _p1);        \
    }                                                                        \
    part[PB][w][r] = _p0 + _p1;                                              \
    asm volatile("s_waitcnt lgkmcnt(0)" ::: "memory");                       \
    asm volatile("s_barrier" ::: "memory");                                  \
    float _hn = fmaf(DDV, h, BUV);                                           \
    _hn += part[PB][0][r]; _hn += part[PB][1][r];                            \
    _hn += part[PB][2][r]; _hn += part[PB][3][r];                            \
    _hn += part[PB][4][r]; _hn += part[PB][5][r];                            \
    _hn += part[PB][6][r]; _hn += part[PB][7][r];                            \
    h = _hn;                                                                 \
    if (w == 0 && (T) >= t0) hout[(base + (size_t)(T)) * 64 + r] = _hn;      \
  } while (0)

  int t = tstart;
  ISSUE(a0, bu0, dd0, t);
  ISSUE(a1, bu1, dd1, t + 1);
  ISSUE(a2, bu2, dd2, t + 2);

  const int ngroups = (tend - tstart) >> 2;
  for (int g = 0; g < ngroups; ++g) {
    { int tp = (t + 3 < tend) ? t + 3 : tend - 1; ISSUE(a3, bu3, dd3, tp); }
    COMPUTE(a0, bu0, dd0, 0, t);
    { int tp = (t + 4 < tend) ? t + 4 : tend - 1; ISSUE(a0, bu0, dd0, tp); }
    COMPUTE(a1, bu1, dd1, 1, t + 1);
    { int tp = (t + 5 < tend) ? t + 5 : tend - 1; ISSUE(a1, bu1, dd1, tp); }
    COMPUTE(a2, bu2, dd2, 0, t + 2);
    { int tp = (t + 6 < tend) ? t + 6 : tend - 1; ISSUE(a2, bu2, dd2, tp); }
    COMPUTE(a3, bu3, dd3, 1, t + 3);
    t += 4;
  }
#undef ISSUE
#undef COMPUTE
}

// ---------------------------------------------------------------------------
// out[m,c] = sum_k h[m,k]*Cw[c,k] + D[c]*u[m,c]
// ---------------------------------------------------------------------------
__global__ __launch_bounds__(256) void out_kernel(
    const float* __restrict__ h, const float* __restrict__ Cw,
    const float* __restrict__ Dv, const float* __restrict__ u,
    float* __restrict__ out)
{
  __shared__ float Cs[128][65];
  const int tid = threadIdx.x;
  const int m0 = blockIdx.x * 32;
  const int c0 = blockIdx.y * 128;

  {
    const float4* src = (const float4*)(Cw + (size_t)c0 * 64);
#pragma unroll
    for (int r = 0; r < 8; ++r) {
      int f = tid + r * 256;
      float4 v = src[f];
      int row = f >> 4, c4 = (f & 15) << 2;
      Cs[row][c4] = v.x; Cs[row][c4 + 1] = v.y; Cs[row][c4 + 2] = v.z; Cs[row][c4 + 3] = v.w;
    }
  }
  __syncthreads();

  const int ci = tid & 127, mg = tid >> 7;
  const int mbase = m0 + mg * 16;
  const float Dc = Dv[c0 + ci];
  float accs[16];
#pragma unroll
  for (int i = 0; i < 16; ++i) accs[i] = 0.f;

  for (int k4 = 0; k4 < 16; ++k4) {
    float c0v = Cs[ci][k4 * 4], c1v = Cs[ci][k4 * 4 + 1];
    float c2v = Cs[ci][k4 * 4 + 2], c3v = Cs[ci][k4 * 4 + 3];
#pragma unroll
    for (int mi = 0; mi < 16; ++mi) {
      float4 hv = *(const float4*)(h + (size_t)(mbase + mi) * 64 + k4 * 4);
      accs[mi] = fmaf(hv.x, c0v, fmaf(hv.y, c1v, fmaf(hv.z, c2v, fmaf(hv.w, c3v, accs[mi]))));
    }
  }
#pragma unroll
  for (int mi = 0; mi < 16; ++mi) {
    size_t row = (size_t)(mbase + mi);
    float uu = u[row * 512 + c0 + ci];
    out[row * 512 + c0 + ci] = accs[mi] + Dc * uu;
  }
}

// ---------------------------------------------------------------------------
extern "C" void kernel_launch(void* const* d_in, const int* in_sizes, int n_in,
                              void* d_out, int out_size, void* d_ws, size_t ws_size,
                              hipStream_t stream) {
  (void)in_sizes; (void)n_in; (void)out_size; (void)ws_size;
  const float* u   = (const float*)d_in[0];
  const float* Wdw = (const float*)d_in[1];
  const float* Wdb = (const float*)d_in[2];
  const float* WAw = (const float*)d_in[3];
  const float* WAb = (const float*)d_in[4];
  const float* WBw = (const float*)d_in[5];
  const float* WBb = (const float*)d_in[6];
  const float* Cw  = (const float*)d_in[7];
  const float* Dv  = (const float*)d_in[8];
  float* out = (float*)d_out;

  char* ws = (char*)d_ws;
  unsigned short* ub    = (unsigned short*)ws; ws += 16777216ull;   // u bf16
  unsigned short* WAb16 = (unsigned short*)ws; ws += 4194304ull;    // W_A bf16 (sigma-permuted rows)
  unsigned short* Wbd   = (unsigned short*)ws; ws += 131072ull;     // W_B|W_d bf16
  unsigned short* Aoff  = (unsigned short*)ws; ws += 134217728ull;  // A' bf16 [t][c*64+r], diag=0
  float* BuA   = (float*)ws; ws += 4194304ull;
  float* dA    = (float*)ws; ws += 4194304ull;
  float* hA    = (float*)ws; ws += 4194304ull;
  float* biasP = (float*)ws; ws += 16384ull;                        // permuted W_A bias

  prep_kernel<<<2048, 256, 0, stream>>>(u, WAw, WBw, Wdw, WAb, ub, WAb16, Wbd, biasP);
  gemm_kernel<1><<<dim3(128, 32), 256, 0, stream>>>(ub, WAb16, biasP, nullptr, Aoff, nullptr, nullptr);
  gemm_kernel<2><<<dim3(128, 1), 256, 0, stream>>>(ub, Wbd, WBb, Wdb, nullptr, BuA, dA);
  scan_kernel<<<dim3(32, 8), 512, 0, stream>>>(Aoff, BuA, dA, hA);
  out_kernel<<<dim3(512, 4), 256, 0, stream>>>(hA, Cw, Dv, u, out);
}

// Round 7
// 354.444 us; speedup vs baseline: 1.1471x; 1.1471x over previous
//
#include <hip/hip_runtime.h>
#include <cstdint>
#include <cstddef>

using short8 = __attribute__((ext_vector_type(8))) short;
using f32x4  = __attribute__((ext_vector_type(4))) float;

#define AS_G __attribute__((address_space(1)))
#define AS_L __attribute__((address_space(3)))

static __device__ __forceinline__ void ld_lds16(const void* g, void* l) {
  __builtin_amdgcn_global_load_lds((const AS_G void*)g, (AS_L void*)l, 16, 0, 0);
}

static __device__ __forceinline__ unsigned short f2bf(float f) {
  unsigned int u = __float_as_uint(f);
  u = u + 0x7fffu + ((u >> 16) & 1u);   // RNE
  return (unsigned short)(u >> 16);
}

// ---------------------------------------------------------------------------
// prep: f32 -> bf16 converts. W_A rows are PERMUTED by sigma(n') = (n'&63)*64
// + (n'>>6) so the GEMM emits A-transpose (A'[t][c*64+r] = A_t[r][c]) with
// packed stores. Also emits the sigma-permuted f32 bias copy.
// ---------------------------------------------------------------------------
__global__ __launch_bounds__(256) void prep_kernel(
    const float* __restrict__ u, const float* __restrict__ WA,
    const float* __restrict__ WB, const float* __restrict__ Wd,
    const float* __restrict__ WAbias,
    unsigned short* __restrict__ ub, unsigned short* __restrict__ WAb,
    unsigned short* __restrict__ Wbd, float* __restrict__ biasP)
{
  const int gtid = blockIdx.x * blockDim.x + threadIdx.x;
  if (gtid < 4096) biasP[gtid] = WAbias[(gtid & 63) * 64 + (gtid >> 6)];

  const int NU = 8388608 / 4;
  const int NA = 2097152 / 4;
  const int NB = 32768 / 4;
  const int ND = 32768 / 4;
  const int total = NU + NA + NB + ND;
  for (int i = gtid; i < total; i += gridDim.x * blockDim.x) {
    const float4* s4; ushort4* d4; int j, sj;
    if (i < NU)                { s4 = (const float4*)u;  d4 = (ushort4*)ub;  j = i; sj = j; }
    else if (i < NU + NA)      { s4 = (const float4*)WA; d4 = (ushort4*)WAb; j = i - NU;
                                 const int row = j >> 7, c4 = j & 127;
                                 sj = ((row & 63) * 64 + (row >> 6)) * 128 + c4; }
    else if (i < NU + NA + NB) { s4 = (const float4*)WB; d4 = (ushort4*)Wbd; j = i - NU - NA; sj = j; }
    else                       { s4 = (const float4*)Wd; d4 = (ushort4*)Wbd + NB; j = i - NU - NA - NB; sj = j; }
    float4 v = s4[sj];
    ushort4 o;
    o.x = f2bf(v.x); o.y = f2bf(v.y); o.z = f2bf(v.z); o.w = f2bf(v.w);
    d4[j] = o;
  }
}

// ---------------------------------------------------------------------------
// GEMM: C[m,n] = sum_k U[m,k]*W[n,k], bf16 MFMA 16x16x32, 128x128 tile, BK=64.
// Single-buffer (R3 structure: best measured), default dispatch order (R1:
// per-XCD m-slice stays L2-resident -> FETCH ~90MB), plain packed 8B stores
// (R3/R6: WRITE 133MB). LDS XOR chunk swizzle; swapped mfma operands.
// EPI=1: A' = tanh(x+biasP)*0.125, diag zeroed, bf16 [M][4096]
// EPI=2: n<64 -> Bu = x+bB (f32); n>=64 -> d = sigmoid(x+bd) (f32)
// ---------------------------------------------------------------------------
template <int EPI>
__global__ __launch_bounds__(256) void gemm_kernel(
    const unsigned short* __restrict__ U,   // [M][512] bf16
    const unsigned short* __restrict__ W,   // [N][512] bf16
    const float* __restrict__ bias0,
    const float* __restrict__ bias1,
    unsigned short* __restrict__ outA,
    float* __restrict__ outBu,
    float* __restrict__ outd)
{
  __shared__ unsigned short lA[128 * 64];   // 16 KB
  __shared__ unsigned short lB[128 * 64];   // 16 KB

  const int tid  = threadIdx.x;
  const int lane = tid & 63;
  const int wv   = tid >> 6;
  const int wuni = __builtin_amdgcn_readfirstlane(wv);
  const int bm = blockIdx.x * 128;
  const int bn = blockIdx.y * 128;

  f32x4 acc[4][4] = {};

  const int r16 = lane & 15, kq = lane >> 4;
  const int wm = (wv >> 1) * 64, wn = (wv & 1) * 64;

  for (int k0 = 0; k0 < 512; k0 += 64) {
#pragma unroll
    for (int l = 0; l < 4; ++l) {
      const int flat = l * 256 + tid;
      const int row  = flat >> 3;
      const int cs   = (flat & 7) ^ (row & 7);
      const int ldsb = (l * 256 + wuni * 64) * 8;
      ld_lds16(U + (size_t)(bm + row) * 512 + k0 + cs * 8, lA + ldsb);
      ld_lds16(W + (size_t)(bn + row) * 512 + k0 + cs * 8, lB + ldsb);
    }
    __syncthreads();                         // drains vmcnt(0): tile ready

#pragma unroll
    for (int kk = 0; kk < 2; ++kk) {
      short8 af[4], bfr[4];
#pragma unroll
      for (int f = 0; f < 4; ++f) {
        const int swz = ((kk * 4 + kq) ^ (r16 & 7)) * 8;
        af[f]  = *(const short8*)&lA[(wm + f * 16 + r16) * 64 + swz];
        bfr[f] = *(const short8*)&lB[(wn + f * 16 + r16) * 64 + swz];
      }
#pragma unroll
      for (int i = 0; i < 4; ++i)
#pragma unroll
        for (int j = 0; j < 4; ++j)
          acc[i][j] = __builtin_amdgcn_mfma_f32_16x16x32_bf16(bfr[j], af[i], acc[i][j], 0, 0, 0);
    }
    __syncthreads();
  }

  const int mrow = lane & 15;
  const int ng   = (lane >> 4) * 4;
#pragma unroll
  for (int i = 0; i < 4; ++i) {
    const int m = bm + wm + i * 16 + mrow;
#pragma unroll
    for (int j = 0; j < 4; ++j) {
      const int nb = bn + wn + j * 16 + ng;
      if (EPI == 1) {
        float4 bi = *(const float4*)(bias0 + nb);
        const float* bp = (const float*)&bi;
        unsigned long long o = 0;
#pragma unroll
        for (int q = 0; q < 4; ++q) {
          const int n = nb + q;
          float z = acc[i][j][q] + bp[q];
          float e = __expf(2.f * z);
          float t = 1.f - 2.f / (e + 1.f);
          float v = (((n & 63) == (n >> 6))) ? 0.f : 0.125f * t;
          o |= ((unsigned long long)f2bf(v)) << (q * 16);
        }
        *(unsigned long long*)(outA + (size_t)m * 4096 + nb) = o;
      } else {
        const int n = wn + j * 16 + ng;
        if (n < 64) {
          float4 bi = *(const float4*)(bias0 + n);
          const float* bp = (const float*)&bi;
          float4 r; float* rp = (float*)&r;
#pragma unroll
          for (int q = 0; q < 4; ++q) rp[q] = acc[i][j][q] + bp[q];
          *(float4*)(outBu + (size_t)m * 64 + n) = r;
        } else {
          float4 bi = *(const float4*)(bias1 + (n - 64));
          const float* bp = (const float*)&bi;
          float4 r; float* rp = (float*)&r;
#pragma unroll
          for (int q = 0; q < 4; ++q) {
            float z = acc[i][j][q] + bp[q];
            rp[q] = 1.f / (1.f + __expf(-z));
          }
          *(float4*)(outd + (size_t)m * 64 + (n - 64)) = r;
        }
      }
    }
  }
}

// ---------------------------------------------------------------------------
// scan v5: h_t[r] = sum_c A_t[r][c] h[c] + d[r]h[r] + Bu[r].
// A' layout [t][c*64+r]. 8 waves/block: wave w owns c in [8w,8w+8). Lane r.
// DEPTH-8 register pipeline (8 named slots, unroll-8 x 16 groups = 128 iters;
// ~64 outstanding loads/wave, HW-capped at 63). Compiler-counted waits; raw
// s_barrier (no vmcnt drain). h replicated in registers per wave; cross-wave
// reduce via double-buffered LDS partials, 1 barrier/iter. Burn-in 64.
// ---------------------------------------------------------------------------
__global__ __launch_bounds__(512) void scan_kernel(
    const unsigned short* __restrict__ At,  // [B*T][4096] = A_t[r][c] at c*64+r
    const float* __restrict__ Bu,           // [B*T][64]
    const float* __restrict__ dg,           // [B*T][64]
    float* __restrict__ hout)               // [B*T][64]
{
  __shared__ float part[2][8][64];

  const int tid = threadIdx.x;
  const int r = tid & 63;
  const int w = tid >> 6;
  const int b = blockIdx.y, ci = blockIdx.x;
  const int t0 = ci * 64, tend = t0 + 64;
  const int tstart = (t0 >= 64) ? (t0 - 64) : 0;
  const size_t base = (size_t)b * 2048;

  float h = 0.f;

  unsigned short a0[8], a1[8], a2[8], a3[8], a4[8], a5[8], a6[8], a7[8];
  float bu0, bu1, bu2, bu3, bu4, bu5, bu6, bu7;
  float dd0, dd1, dd2, dd3, dd4, dd5, dd6, dd7;

#define ISSUE(AV, BUV, DDV, T) do {                                          \
    const size_t _m = base + (size_t)(T);                                    \
    const unsigned short* _p = At + _m * 4096 + (w * 8) * 64 + r;            \
    _Pragma("unroll") for (int q = 0; q < 8; ++q) AV[q] = _p[q * 64];        \
    BUV = Bu[_m * 64 + r];                                                   \
    DDV = dg[_m * 64 + r];                                                   \
  } while (0)

#define COMPUTE(AV, BUV, DDV, PB, T) do {                                    \
    float _p0 = 0.f, _p1 = 0.f;                                              \
    _Pragma("unroll") for (int q = 0; q < 4; ++q) {                          \
      float _hv = __uint_as_float(                                           \
          __builtin_amdgcn_readlane(__float_as_uint(h), w * 8 + q));         \
      _p0 = fmaf(__uint_as_float(((unsigned)AV[q]) << 16), _hv, _p0);        \
    }                                                                        \
    _Pragma("unroll") for (int q = 4; q < 8; ++q) {                          \
      float _hv = __uint_as_float(                                           \
          __builtin_amdgcn_readlane(__float_as_uint(h), w * 8 + q));         \
      _p1 = fmaf(__uint_as_float(((unsigned)AV[q]) << 16), _hv, _p1);        \
    }                                                                        \
    part[PB][w][r] = _p0 + _p1;                                              \
    asm volatile("s_waitcnt lgkmcnt(0)" ::: "memory");                       \
    asm volatile("s_barrier" ::: "memory");                                  \
    float _hn = fmaf(DDV, h, BUV);                                           \
    _hn += part[PB][0][r]; _hn += part[PB][1][r];                            \
    _hn += part[PB][2][r]; _hn += part[PB][3][r];                            \
    _hn += part[PB][4][r]; _hn += part[PB][5][r];                            \
    _hn += part[PB][6][r]; _hn += part[PB][7][r];                            \
    h = _hn;                                                                 \
    if (w == 0 && (T) >= t0) hout[(base + (size_t)(T)) * 64 + r] = _hn;      \
  } while (0)

#define CLAMP(X) ((X) < tend ? (X) : (tend - 1))

  int t = tstart;
  ISSUE(a0, bu0, dd0, t);
  ISSUE(a1, bu1, dd1, CLAMP(t + 1));
  ISSUE(a2, bu2, dd2, CLAMP(t + 2));
  ISSUE(a3, bu3, dd3, CLAMP(t + 3));
  ISSUE(a4, bu4, dd4, CLAMP(t + 4));
  ISSUE(a5, bu5, dd5, CLAMP(t + 5));
  ISSUE(a6, bu6, dd6, CLAMP(t + 6));

  const int ngroups = (tend - tstart) >> 3;   // 128/8 = 16
  for (int g = 0; g < ngroups; ++g) {
    ISSUE(a7, bu7, dd7, CLAMP(t + 7));  COMPUTE(a0, bu0, dd0, 0, t);
    ISSUE(a0, bu0, dd0, CLAMP(t + 8));  COMPUTE(a1, bu1, dd1, 1, t + 1);
    ISSUE(a1, bu1, dd1, CLAMP(t + 9));  COMPUTE(a2, bu2, dd2, 0, t + 2);
    ISSUE(a2, bu2, dd2, CLAMP(t + 10)); COMPUTE(a3, bu3, dd3, 1, t + 3);
    ISSUE(a3, bu3, dd3, CLAMP(t + 11)); COMPUTE(a4, bu4, dd4, 0, t + 4);
    ISSUE(a4, bu4, dd4, CLAMP(t + 12)); COMPUTE(a5, bu5, dd5, 1, t + 5);
    ISSUE(a5, bu5, dd5, CLAMP(t + 13)); COMPUTE(a6, bu6, dd6, 0, t + 6);
    ISSUE(a6, bu6, dd6, CLAMP(t + 14)); COMPUTE(a7, bu7, dd7, 1, t + 7);
    t += 8;
  }
#undef ISSUE
#undef COMPUTE
#undef CLAMP
}

// ---------------------------------------------------------------------------
// out[m,c] = sum_k h[m,k]*Cw[c,k] + D[c]*u[m,c]
// ---------------------------------------------------------------------------
__global__ __launch_bounds__(256) void out_kernel(
    const float* __restrict__ h, const float* __restrict__ Cw,
    const float* __restrict__ Dv, const float* __restrict__ u,
    float* __restrict__ out)
{
  __shared__ float Cs[128][65];
  const int tid = threadIdx.x;
  const int m0 = blockIdx.x * 32;
  const int c0 = blockIdx.y * 128;

  {
    const float4* src = (const float4*)(Cw + (size_t)c0 * 64);
#pragma unroll
    for (int r = 0; r < 8; ++r) {
      int f = tid + r * 256;
      float4 v = src[f];
      int row = f >> 4, c4 = (f & 15) << 2;
      Cs[row][c4] = v.x; Cs[row][c4 + 1] = v.y; Cs[row][c4 + 2] = v.z; Cs[row][c4 + 3] = v.w;
    }
  }
  __syncthreads();

  const int ci = tid & 127, mg = tid >> 7;
  const int mbase = m0 + mg * 16;
  const float Dc = Dv[c0 + ci];
  float accs[16];
#pragma unroll
  for (int i = 0; i < 16; ++i) accs[i] = 0.f;

  for (int k4 = 0; k4 < 16; ++k4) {
    float c0v = Cs[ci][k4 * 4], c1v = Cs[ci][k4 * 4 + 1];
    float c2v = Cs[ci][k4 * 4 + 2], c3v = Cs[ci][k4 * 4 + 3];
#pragma unroll
    for (int mi = 0; mi < 16; ++mi) {
      float4 hv = *(const float4*)(h + (size_t)(mbase + mi) * 64 + k4 * 4);
      accs[mi] = fmaf(hv.x, c0v, fmaf(hv.y, c1v, fmaf(hv.z, c2v, fmaf(hv.w, c3v, accs[mi]))));
    }
  }
#pragma unroll
  for (int mi = 0; mi < 16; ++mi) {
    size_t row = (size_t)(mbase + mi);
    float uu = u[row * 512 + c0 + ci];
    out[row * 512 + c0 + ci] = accs[mi] + Dc * uu;
  }
}

// ---------------------------------------------------------------------------
extern "C" void kernel_launch(void* const* d_in, const int* in_sizes, int n_in,
                              void* d_out, int out_size, void* d_ws, size_t ws_size,
                              hipStream_t stream) {
  (void)in_sizes; (void)n_in; (void)out_size; (void)ws_size;
  const float* u   = (const float*)d_in[0];
  const float* Wdw = (const float*)d_in[1];
  const float* Wdb = (const float*)d_in[2];
  const float* WAw = (const float*)d_in[3];
  const float* WAb = (const float*)d_in[4];
  const float* WBw = (const float*)d_in[5];
  const float* WBb = (const float*)d_in[6];
  const float* Cw  = (const float*)d_in[7];
  const float* Dv  = (const float*)d_in[8];
  float* out = (float*)d_out;

  char* ws = (char*)d_ws;
  unsigned short* ub    = (unsigned short*)ws; ws += 16777216ull;   // u bf16
  unsigned short* WAb16 = (unsigned short*)ws; ws += 4194304ull;    // W_A bf16 (sigma-permuted rows)
  unsigned short* Wbd   = (unsigned short*)ws; ws += 131072ull;     // W_B|W_d bf16
  unsigned short* Aoff  = (unsigned short*)ws; ws += 134217728ull;  // A' bf16 [t][c*64+r], diag=0
  float* BuA   = (float*)ws; ws += 4194304ull;
  float* dA    = (float*)ws; ws += 4194304ull;
  float* hA    = (float*)ws; ws += 4194304ull;
  float* biasP = (float*)ws; ws += 16384ull;                        // permuted W_A bias

  prep_kernel<<<2048, 256, 0, stream>>>(u, WAw, WBw, Wdw, WAb, ub, WAb16, Wbd, biasP);
  gemm_kernel<1><<<dim3(128, 32), 256, 0, stream>>>(ub, WAb16, biasP, nullptr, Aoff, nullptr, nullptr);
  gemm_kernel<2><<<dim3(128, 1), 256, 0, stream>>>(ub, Wbd, WBb, Wdb, nullptr, BuA, dA);
  scan_kernel<<<dim3(32, 8), 512, 0, stream>>>(Aoff, BuA, dA, hA);
  out_kernel<<<dim3(512, 4), 256, 0, stream>>>(hA, Cw, Dv, u, out);
}

// Round 8
// 340.340 us; speedup vs baseline: 1.1947x; 1.0414x over previous
//
#include <hip/hip_runtime.h>
#include <cstdint>
#include <cstddef>

using short8 = __attribute__((ext_vector_type(8))) short;
using f32x4  = __attribute__((ext_vector_type(4))) float;

#define AS_G __attribute__((address_space(1)))
#define AS_L __attribute__((address_space(3)))

static __device__ __forceinline__ void ld_lds16(const void* g, void* l) {
  __builtin_amdgcn_global_load_lds((const AS_G void*)g, (AS_L void*)l, 16, 0, 0);
}

static __device__ __forceinline__ unsigned short f2bf(float f) {
  unsigned int u = __float_as_uint(f);
  u = u + 0x7fffu + ((u >> 16) & 1u);   // RNE
  return (unsigned short)(u >> 16);
}

// ---------------------------------------------------------------------------
// prep: f32 -> bf16 converts (u, W_A natural order, W_B|W_d stacked [128][512])
// ---------------------------------------------------------------------------
__global__ __launch_bounds__(256) void prep_kernel(
    const float* __restrict__ u, const float* __restrict__ WA,
    const float* __restrict__ WB, const float* __restrict__ Wd,
    unsigned short* __restrict__ ub, unsigned short* __restrict__ WAb,
    unsigned short* __restrict__ Wbd)
{
  const int NU = 8388608 / 4;
  const int NA = 2097152 / 4;
  const int NB = 32768 / 4;
  const int ND = 32768 / 4;
  const int total = NU + NA + NB + ND;
  for (int i = blockIdx.x * blockDim.x + threadIdx.x; i < total;
       i += gridDim.x * blockDim.x) {
    const float4* s4; ushort4* d4; int j;
    if (i < NU)                { s4 = (const float4*)u;  d4 = (ushort4*)ub;  j = i; }
    else if (i < NU + NA)      { s4 = (const float4*)WA; d4 = (ushort4*)WAb; j = i - NU; }
    else if (i < NU + NA + NB) { s4 = (const float4*)WB; d4 = (ushort4*)Wbd; j = i - NU - NA; }
    else                       { s4 = (const float4*)Wd; d4 = (ushort4*)Wbd + NB; j = i - NU - NA - NB; }
    float4 v = s4[j];
    ushort4 o;
    o.x = f2bf(v.x); o.y = f2bf(v.y); o.z = f2bf(v.z); o.w = f2bf(v.w);
    d4[j] = o;
  }
}

// ---------------------------------------------------------------------------
// GEMM: C[m,n] = sum_k U[m,k]*W[n,k], bf16 MFMA 16x16x32, 128x128 tile, BK=32.
// 2-phase double-buffer, COUNTED vmcnt(4) in-loop (never 0 until last step):
//   vmcnt(4); barrier; ds_read frags; lgkmcnt(0); barrier; stage(ks+2); MFMA
// LDS 2x8KB per matrix = 32 KB total (occupancy preserved vs R6's 64KB fail).
// XOR chunk swizzle over 4 chunks (4-way read conflict accepted; DS not the
// bottleneck). Swapped mfma operands -> lane holds 4 consecutive n -> 8B
// packed stores. Default dispatch order (R1/R7: FETCH ~84MB).
// EPI=1: A = tanh(x+bias)*0.125, diag (n%64==n/64) zeroed, bf16 [M][4096]
// EPI=2: n<64 -> Bu = x+bB (f32); n>=64 -> d = sigmoid(x+bd) (f32)
// ---------------------------------------------------------------------------
template <int EPI>
__global__ __launch_bounds__(256) void gemm_kernel(
    const unsigned short* __restrict__ U,   // [M][512] bf16
    const unsigned short* __restrict__ W,   // [N][512] bf16
    const float* __restrict__ bias0,
    const float* __restrict__ bias1,
    unsigned short* __restrict__ outA,
    float* __restrict__ outBu,
    float* __restrict__ outd)
{
  __shared__ unsigned short lA[2][128 * 32];   // 2 x 8 KB
  __shared__ unsigned short lB[2][128 * 32];   // 2 x 8 KB

  const int tid  = threadIdx.x;
  const int lane = tid & 63;
  const int wv   = tid >> 6;
  const int wuni = __builtin_amdgcn_readfirstlane(wv);
  const int bm = blockIdx.x * 128;
  const int bn = blockIdx.y * 128;

  f32x4 acc[4][4] = {};

  const int r16 = lane & 15, kq = lane >> 4;
  const int wm = (wv >> 1) * 64, wn = (wv & 1) * 64;

  // stage one BK=32 tile pair into buf: 512 slots x 16B per matrix,
  // slot s -> row = s>>2, phys chunk = s&3 holds logical chunk (s&3)^(row&3)
  auto stage = [&](int buf, int ks) {
    const int k0 = ks * 32;
#pragma unroll
    for (int l = 0; l < 2; ++l) {
      const int s    = l * 256 + tid;
      const int row  = s >> 2;
      const int cs   = (s & 3) ^ (row & 3);
      const int ldsb = (l * 256 + wuni * 64) * 8;   // ushort units, linear dest
      ld_lds16(U + (size_t)(bm + row) * 512 + k0 + cs * 8, &lA[buf][ldsb]);
      ld_lds16(W + (size_t)(bn + row) * 512 + k0 + cs * 8, &lB[buf][ldsb]);
    }
  };

  stage(0, 0);
  stage(1, 1);

#define GEMM_STEP(KS, LAST)                                                   \
  do {                                                                        \
    if (LAST) { asm volatile("s_waitcnt vmcnt(0)" ::: "memory"); }            \
    else      { asm volatile("s_waitcnt vmcnt(4)" ::: "memory"); }            \
    __builtin_amdgcn_s_barrier();          /* buf[cb] ready for all waves */  \
    const int cb = (KS) & 1;                                                  \
    short8 af[4], bfr[4];                                                     \
    _Pragma("unroll")                                                         \
    for (int f = 0; f < 4; ++f) {                                             \
      const int swz = (kq ^ (r16 & 3)) * 8;                                   \
      af[f]  = *(const short8*)&lA[cb][(wm + f * 16 + r16) * 32 + swz];       \
      bfr[f] = *(const short8*)&lB[cb][(wn + f * 16 + r16) * 32 + swz];       \
    }                                                                         \
    asm volatile("s_waitcnt lgkmcnt(0)" ::: "memory");                        \
    __builtin_amdgcn_sched_barrier(0);                                        \
    __builtin_amdgcn_s_barrier();          /* all waves consumed buf[cb] */   \
    if ((KS) + 2 < 16) stage(cb, (KS) + 2);                                   \
    _Pragma("unroll")                                                         \
    for (int i = 0; i < 4; ++i)                                               \
      _Pragma("unroll")                                                       \
      for (int j = 0; j < 4; ++j)                                             \
        acc[i][j] = __builtin_amdgcn_mfma_f32_16x16x32_bf16(                  \
            bfr[j], af[i], acc[i][j], 0, 0, 0);                               \
  } while (0)

  for (int ks = 0; ks < 15; ++ks) GEMM_STEP(ks, false);
  GEMM_STEP(15, true);
#undef GEMM_STEP

  // epilogue: lane holds C[m][n0..n0+3], m = bm+wm+i*16+(lane&15),
  //           n0 = bn+wn+j*16+(lane>>4)*4
  const int mrow = lane & 15;
  const int ng   = (lane >> 4) * 4;
#pragma unroll
  for (int i = 0; i < 4; ++i) {
    const int m = bm + wm + i * 16 + mrow;
#pragma unroll
    for (int j = 0; j < 4; ++j) {
      const int nb = bn + wn + j * 16 + ng;
      if (EPI == 1) {
        float4 bi = *(const float4*)(bias0 + nb);
        const float* bp = (const float*)&bi;
        unsigned long long o = 0;
#pragma unroll
        for (int q = 0; q < 4; ++q) {
          const int n = nb + q;
          float z = acc[i][j][q] + bp[q];
          float e = __expf(2.f * z);
          float t = 1.f - 2.f / (e + 1.f);
          float v = (((n & 63) == (n >> 6))) ? 0.f : 0.125f * t;
          o |= ((unsigned long long)f2bf(v)) << (q * 16);
        }
        *(unsigned long long*)(outA + (size_t)m * 4096 + nb) = o;
      } else {
        const int n = wn + j * 16 + ng;
        if (n < 64) {
          float4 bi = *(const float4*)(bias0 + n);
          const float* bp = (const float*)&bi;
          float4 r; float* rp = (float*)&r;
#pragma unroll
          for (int q = 0; q < 4; ++q) rp[q] = acc[i][j][q] + bp[q];
          *(float4*)(outBu + (size_t)m * 64 + n) = r;
        } else {
          float4 bi = *(const float4*)(bias1 + (n - 64));
          const float* bp = (const float*)&bi;
          float4 r; float* rp = (float*)&r;
#pragma unroll
          for (int q = 0; q < 4; ++q) {
            float z = acc[i][j][q] + bp[q];
            rp[q] = 1.f / (1.f + __expf(-z));
          }
          *(float4*)(outd + (size_t)m * 64 + (n - 64)) = r;
        }
      }
    }
  }
}

// ---------------------------------------------------------------------------
// scan v6: h_t[r] = sum_c A_t[r][c] h[c] + d[r]h[r] + Bu[r].
// ROW-MAJOR A [t][r*64+c]. 8 waves/block: wave w owns c in [8w,8w+8). Lane r
// loads its own row slice as ONE uint4 (16B) per tile (3 VMEM/iter/wave vs
// v5's 10); waves 0..7 jointly cover each 64B line within one barrier-synced
// iter (L1 merges). Depth-8 register pipeline; h replicated in registers;
// cross-wave reduce via double-buffered LDS partials, 1 barrier/iter.
// Burn-in 64 (measured: absmax 9.2e-4).
// ---------------------------------------------------------------------------
__global__ __launch_bounds__(512) void scan_kernel(
    const unsigned short* __restrict__ Ag,  // [B*T][4096] row-major, diag=0
    const float* __restrict__ Bu,           // [B*T][64]
    const float* __restrict__ dg,           // [B*T][64]
    float* __restrict__ hout)               // [B*T][64]
{
  __shared__ float part[2][8][64];

  const int tid = threadIdx.x;
  const int r = tid & 63;
  const int w = tid >> 6;
  const int b = blockIdx.y, ci = blockIdx.x;
  const int t0 = ci * 64, tend = t0 + 64;
  const int tstart = (t0 >= 64) ? (t0 - 64) : 0;
  const size_t base = (size_t)b * 2048;

  float h = 0.f;

  uint4 a0, a1, a2, a3, a4, a5, a6, a7;
  float bu0, bu1, bu2, bu3, bu4, bu5, bu6, bu7;
  float dd0, dd1, dd2, dd3, dd4, dd5, dd6, dd7;

#define ISSUE(AV, BUV, DDV, T) do {                                          \
    const size_t _m = base + (size_t)(T);                                    \
    AV = *(const uint4*)(Ag + _m * 4096 + r * 64 + w * 8);                   \
    BUV = Bu[_m * 64 + r];                                                   \
    DDV = dg[_m * 64 + r];                                                   \
  } while (0)

#define COMPUTE(AV, BUV, DDV, PB, T) do {                                    \
    float _h0 = __uint_as_float(__builtin_amdgcn_readlane(__float_as_uint(h), w * 8 + 0)); \
    float _h1 = __uint_as_float(__builtin_amdgcn_readlane(__float_as_uint(h), w * 8 + 1)); \
    float _h2 = __uint_as_float(__builtin_amdgcn_readlane(__float_as_uint(h), w * 8 + 2)); \
    float _h3 = __uint_as_float(__builtin_amdgcn_readlane(__float_as_uint(h), w * 8 + 3)); \
    float _h4 = __uint_as_float(__builtin_amdgcn_readlane(__float_as_uint(h), w * 8 + 4)); \
    float _h5 = __uint_as_float(__builtin_amdgcn_readlane(__float_as_uint(h), w * 8 + 5)); \
    float _h6 = __uint_as_float(__builtin_amdgcn_readlane(__float_as_uint(h), w * 8 + 6)); \
    float _h7 = __uint_as_float(__builtin_amdgcn_readlane(__float_as_uint(h), w * 8 + 7)); \
    float _p0 = 0.f, _p1 = 0.f;                                              \
    _p0 = fmaf(__uint_as_float(AV.x << 16),         _h0, _p0);               \
    _p0 = fmaf(__uint_as_float(AV.x & 0xffff0000u), _h1, _p0);               \
    _p0 = fmaf(__uint_as_float(AV.y << 16),         _h2, _p0);               \
    _p0 = fmaf(__uint_as_float(AV.y & 0xffff0000u), _h3, _p0);               \
    _p1 = fmaf(__uint_as_float(AV.z << 16),         _h4, _p1);               \
    _p1 = fmaf(__uint_as_float(AV.z & 0xffff0000u), _h5, _p1);               \
    _p1 = fmaf(__uint_as_float(AV.w << 16),         _h6, _p1);               \
    _p1 = fmaf(__uint_as_float(AV.w & 0xffff0000u), _h7, _p1);               \
    part[PB][w][r] = _p0 + _p1;                                              \
    asm volatile("s_waitcnt lgkmcnt(0)" ::: "memory");                       \
    asm volatile("s_barrier" ::: "memory");                                  \
    float _hn = fmaf(DDV, h, BUV);                                           \
    _hn += part[PB][0][r]; _hn += part[PB][1][r];                            \
    _hn += part[PB][2][r]; _hn += part[PB][3][r];                            \
    _hn += part[PB][4][r]; _hn += part[PB][5][r];                            \
    _hn += part[PB][6][r]; _hn += part[PB][7][r];                            \
    h = _hn;                                                                 \
    if (w == 0 && (T) >= t0) hout[(base + (size_t)(T)) * 64 + r] = _hn;      \
  } while (0)

#define CLAMP(X) ((X) < tend ? (X) : (tend - 1))

  int t = tstart;
  ISSUE(a0, bu0, dd0, t);
  ISSUE(a1, bu1, dd1, CLAMP(t + 1));
  ISSUE(a2, bu2, dd2, CLAMP(t + 2));
  ISSUE(a3, bu3, dd3, CLAMP(t + 3));
  ISSUE(a4, bu4, dd4, CLAMP(t + 4));
  ISSUE(a5, bu5, dd5, CLAMP(t + 5));
  ISSUE(a6, bu6, dd6, CLAMP(t + 6));

  const int ngroups = (tend - tstart) >> 3;   // 128/8 = 16
  for (int g = 0; g < ngroups; ++g) {
    ISSUE(a7, bu7, dd7, CLAMP(t + 7));  COMPUTE(a0, bu0, dd0, 0, t);
    ISSUE(a0, bu0, dd0, CLAMP(t + 8));  COMPUTE(a1, bu1, dd1, 1, t + 1);
    ISSUE(a1, bu1, dd1, CLAMP(t + 9));  COMPUTE(a2, bu2, dd2, 0, t + 2);
    ISSUE(a2, bu2, dd2, CLAMP(t + 10)); COMPUTE(a3, bu3, dd3, 1, t + 3);
    ISSUE(a3, bu3, dd3, CLAMP(t + 11)); COMPUTE(a4, bu4, dd4, 0, t + 4);
    ISSUE(a4, bu4, dd4, CLAMP(t + 12)); COMPUTE(a5, bu5, dd5, 1, t + 5);
    ISSUE(a5, bu5, dd5, CLAMP(t + 13)); COMPUTE(a6, bu6, dd6, 0, t + 6);
    ISSUE(a6, bu6, dd6, CLAMP(t + 14)); COMPUTE(a7, bu7, dd7, 1, t + 7);
    t += 8;
  }
#undef ISSUE
#undef COMPUTE
#undef CLAMP
}

// ---------------------------------------------------------------------------
// out[m,c] = sum_k h[m,k]*Cw[c,k] + D[c]*u[m,c]
// ---------------------------------------------------------------------------
__global__ __launch_bounds__(256) void out_kernel(
    const float* __restrict__ h, const float* __restrict__ Cw,
    const float* __restrict__ Dv, const float* __restrict__ u,
    float* __restrict__ out)
{
  __shared__ float Cs[128][65];
  const int tid = threadIdx.x;
  const int m0 = blockIdx.x * 32;
  const int c0 = blockIdx.y * 128;

  {
    const float4* src = (const float4*)(Cw + (size_t)c0 * 64);
#pragma unroll
    for (int r = 0; r < 8; ++r) {
      int f = tid + r * 256;
      float4 v = src[f];
      int row = f >> 4, c4 = (f & 15) << 2;
      Cs[row][c4] = v.x; Cs[row][c4 + 1] = v.y; Cs[row][c4 + 2] = v.z; Cs[row][c4 + 3] = v.w;
    }
  }
  __syncthreads();

  const int ci = tid & 127, mg = tid >> 7;
  const int mbase = m0 + mg * 16;
  const float Dc = Dv[c0 + ci];
  float accs[16];
#pragma unroll
  for (int i = 0; i < 16; ++i) accs[i] = 0.f;

  for (int k4 = 0; k4 < 16; ++k4) {
    float c0v = Cs[ci][k4 * 4], c1v = Cs[ci][k4 * 4 + 1];
    float c2v = Cs[ci][k4 * 4 + 2], c3v = Cs[ci][k4 * 4 + 3];
#pragma unroll
    for (int mi = 0; mi < 16; ++mi) {
      float4 hv = *(const float4*)(h + (size_t)(mbase + mi) * 64 + k4 * 4);
      accs[mi] = fmaf(hv.x, c0v, fmaf(hv.y, c1v, fmaf(hv.z, c2v, fmaf(hv.w, c3v, accs[mi]))));
    }
  }
#pragma unroll
  for (int mi = 0; mi < 16; ++mi) {
    size_t row = (size_t)(mbase + mi);
    float uu = u[row * 512 + c0 + ci];
    out[row * 512 + c0 + ci] = accs[mi] + Dc * uu;
  }
}

// ---------------------------------------------------------------------------
extern "C" void kernel_launch(void* const* d_in, const int* in_sizes, int n_in,
                              void* d_out, int out_size, void* d_ws, size_t ws_size,
                              hipStream_t stream) {
  (void)in_sizes; (void)n_in; (void)out_size; (void)ws_size;
  const float* u   = (const float*)d_in[0];
  const float* Wdw = (const float*)d_in[1];
  const float* Wdb = (const float*)d_in[2];
  const float* WAw = (const float*)d_in[3];
  const float* WAb = (const float*)d_in[4];
  const float* WBw = (const float*)d_in[5];
  const float* WBb = (const float*)d_in[6];
  const float* Cw  = (const float*)d_in[7];
  const float* Dv  = (const float*)d_in[8];
  float* out = (float*)d_out;

  char* ws = (char*)d_ws;
  unsigned short* ub    = (unsigned short*)ws; ws += 16777216ull;   // u bf16
  unsigned short* WAb16 = (unsigned short*)ws; ws += 4194304ull;    // W_A bf16
  unsigned short* Wbd   = (unsigned short*)ws; ws += 131072ull;     // W_B|W_d bf16
  unsigned short* Aoff  = (unsigned short*)ws; ws += 134217728ull;  // A bf16 row-major, diag=0
  float* BuA   = (float*)ws; ws += 4194304ull;
  float* dA    = (float*)ws; ws += 4194304ull;
  float* hA    = (float*)ws; ws += 4194304ull;

  prep_kernel<<<2048, 256, 0, stream>>>(u, WAw, WBw, Wdw, ub, WAb16, Wbd);
  gemm_kernel<1><<<dim3(128, 32), 256, 0, stream>>>(ub, WAb16, WAb, nullptr, Aoff, nullptr, nullptr);
  gemm_kernel<2><<<dim3(128, 1), 256, 0, stream>>>(ub, Wbd, WBb, Wdb, nullptr, BuA, dA);
  scan_kernel<<<dim3(32, 8), 512, 0, stream>>>(Aoff, BuA, dA, hA);
  out_kernel<<<dim3(512, 4), 256, 0, stream>>>(hA, Cw, Dv, u, out);
}